// Round 11
// baseline (18047.220 us; speedup 1.0000x reference)
//
#include <hip/hip_runtime.h>

typedef unsigned short u16;
typedef unsigned int   u32;

typedef __bf16 bf16x8 __attribute__((ext_vector_type(8)));
typedef float  f32x4  __attribute__((ext_vector_type(4)));

#define NB   64
#define NS   512
#define NE   512
#define NH   1024
#define NK   1536
#define NV   32000

#define WPKF_BYTES  12582912u   // bf16 frags [128 cg][48 kt][2 f][64 lane][8]
#define HFRAG_BYTES 262144u     // bf16 frags 2 par x [4 bg][32 kt][64 lane][8]
#define AEMBF_BYTES 33554432u   // bf16 frags [512 s][4 bg][16 kt][64 lane][8]
#define BSUM_BYTES  16384u      // f32 [4096]
#define BAR_BYTES   4096u       // u32 counters

__device__ __forceinline__ u16 f2bf(float f) {
    u32 u = __builtin_bit_cast(u32, f);
    u += 0x7fffu + ((u >> 16) & 1u);       // RNE
    return (u16)(u >> 16);
}
__device__ __forceinline__ bf16x8 pack8(float4 a, float4 b) {
    union { u16 u[8]; bf16x8 v; } o;
    o.u[0]=f2bf(a.x); o.u[1]=f2bf(a.y); o.u[2]=f2bf(a.z); o.u[3]=f2bf(a.w);
    o.u[4]=f2bf(b.x); o.u[5]=f2bf(b.y); o.u[6]=f2bf(b.z); o.u[7]=f2bf(b.w);
    return o.v;
}
__device__ __forceinline__ float sigf(float x) {
    return 1.0f / (1.0f + expf(-x));
}
__device__ __forceinline__ int clamptok(int t) {
    return t < 0 ? 0 : (t >= NV ? NV - 1 : t);
}

// ---------------------------------------------------------------------------
// Prep kernels (proven in R9/R10)
// ---------------------------------------------------------------------------
__global__ void init_state(const float* __restrict__ h0,
                           const float* __restrict__ c0,
                           float* __restrict__ out) {
    int i = blockIdx.x * 256 + threadIdx.x;
    float* out_h = out + 64;
    float* out_c = out + 64 + NB * NH;
    ((float4*)out_h)[i] = ((const float4*)h0)[i];
    ((float4*)out_c)[i] = ((const float4*)c0)[i];
}

__global__ void init_hfrag(const float* __restrict__ h0,
                           u16* __restrict__ hfrag0) {
    int blk = blockIdx.x, lane = threadIdx.x;
    int bg = blk >> 5, kt = blk & 31;
    int n16 = lane & 15, quad = lane >> 4;
    int b = bg * 16 + n16;
    int k = kt * 32 + quad * 8;
    const float* src = h0 + (size_t)b * NH + k;
    union { bf16x8 v; uint4 q; } o;
    o.v = pack8(*(const float4*)src, *(const float4*)(src + 4));
    *(uint4*)(hfrag0 + ((size_t)blk * 64 + lane) * 8) = o.q;
}

__global__ void prep_wfrag(const float* __restrict__ Wih,
                           const float* __restrict__ Whh,
                           u16* __restrict__ wpkf) {
    int blk = blockIdx.x, t = threadIdx.x;
    int cg = blk / 48, kt = blk % 48;
    int f = t >> 6, lane = t & 63;
    int n16 = lane & 15, quad = lane >> 4;
    int nl = f * 16 + n16;
    int j = (nl >> 3) * NH + cg * 8 + (nl & 7);
    int k = kt * 32 + quad * 8;
    const float* src = (k < NH) ? (Whh + (size_t)j * NH + k)
                                : (Wih + (size_t)j * NE + (k - NH));
    union { bf16x8 v; uint4 q; } o;
    o.v = pack8(*(const float4*)src, *(const float4*)(src + 4));
    *(uint4*)(wpkf + (((size_t)blk * 2 + f) * 64 + lane) * 8) = o.q;
}

__global__ void prep_aembf(const int* __restrict__ x,
                           const float* __restrict__ emb,
                           u16* __restrict__ aembf) {
    int blk = blockIdx.x, t = threadIdx.x;
    int s = blk >> 2, bg = blk & 3;
#pragma unroll
    for (int i = 0; i < 4; ++i) {
        int u = t + i * 256;
        int kt16 = u >> 6, lane = u & 63;
        int n16 = lane & 15, quad = lane >> 4;
        int b = bg * 16 + n16;
        int tok = clamptok(x[b * NS + s]);
        const float* ep = emb + (size_t)tok * NE + kt16 * 32 + quad * 8;
        union { bf16x8 v; uint4 q; } o;
        o.v = pack8(*(const float4*)ep, *(const float4*)(ep + 4));
        *(uint4*)(aembf + (((size_t)blk * 16 + kt16) * 64 + lane) * 8) = o.q;
    }
}

__global__ void prep_bsum(const float* __restrict__ bih,
                          const float* __restrict__ bhh,
                          float* __restrict__ bsum) {
    int i = blockIdx.x * 256 + threadIdx.x;
    bsum[i] = bih[i] + bhh[i];
}

__global__ void zero_bar(u32* __restrict__ bar) {
    ((uint4*)bar)[threadIdx.x] = uint4{0, 0, 0, 0};   // 256*16B = 4 KB
}

// ---------------------------------------------------------------------------
// PERSISTENT cooperative LSTM. 256 blocks x 256 thr.
//   blk: cg = blk & 127 (XCD swizzle), bgp = blk >> 7 (32 batches b0=bgp*32).
//   Wave w preloads its 12 kt x 2 B-frags of cg's weight slice -> 96 VGPRs,
//   held across all 512 steps. c state: 1 f32 reg per thread (batch, unit).
//   Per step: 48 MFMA/wave, h/emb frag reads (L2), LDS reduce, epilogue,
//   h scatter to hfrag parity buffer, 2-level atomic grid barrier.
// bar: c1[grp] at bar[grp*32] (8 groups of 32 blocks), c2 at bar[256],
//      gen at bar[320]. Monotonic counters; zeroed per call by zero_bar.
// ---------------------------------------------------------------------------
__global__ void __launch_bounds__(256, 1)
lstm_persist(const u16* __restrict__ wpkf, const u16* __restrict__ aembf,
             u16* __restrict__ hf0, u16* __restrict__ hf1,
             const float* __restrict__ c0, const float* __restrict__ bsum,
             u32* __restrict__ bar, float* __restrict__ out) {
    const int tid  = threadIdx.x;
    const int lane = tid & 63;
    const int w    = tid >> 6;
    const int blk  = blockIdx.x;
    const int cg   = blk & 127;
    const int bgp  = blk >> 7;             // 0..1
    const int n16  = lane & 15;

    __shared__ float part[4][32][33];

    // ---- preload weight fragments into registers ----
    const u16* wb = wpkf + (size_t)cg * 48 * 2 * 64 * 8;
    bf16x8 wf[12][2];
#pragma unroll
    for (int tkt = 0; tkt < 12; ++tkt) {
        int kt = w * 12 + tkt;
#pragma unroll
        for (int f = 0; f < 2; ++f)
            wf[tkt][f] = *(const bf16x8*)(wb + (((size_t)kt * 2 + f) * 64 + lane) * 8);
    }

    // ---- per-thread epilogue constants ----
    const int mloc = tid >> 3;             // 0..31 (batch in block)
    const int uu   = tid & 7;              // 0..7
    const int be   = bgp * 32 + mloc;
    const int je   = cg * 8 + uu;
    float bias_g[4];
#pragma unroll
    for (int g = 0; g < 4; ++g) bias_g[g] = bsum[g * NH + je];
    float c_reg = c0[be * NH + je];

    // h scatter address (constant across steps except parity base)
    const int kth   = je >> 5;
    const int rr    = je & 31;
    const int lane2 = (rr >> 3) * 16 + (mloc & 15);
    const int bg_e  = bgp * 2 + (mloc >> 4);
    const size_t hsc = ((size_t)(bg_e * 32 + kth) * 64 + lane2) * 8 + (rr & 7);

    float* out_h = out + 64;
    float* out_c = out + 64 + NB * NH;
    const u32 grp = (u32)(blk >> 5);       // 8 groups of 32

    for (int s = 0; s < NS; ++s) {
        const u16* hfA = (s & 1) ? hf1 : hf0;
        u16*       hfB = (s & 1) ? hf0 : hf1;

        const u16* hb0 = hfA + (size_t)(bgp * 2 + 0) * 32 * 64 * 8;
        const u16* hb1 = hfA + (size_t)(bgp * 2 + 1) * 32 * 64 * 8;
        const u16* eb0 = aembf + ((size_t)(s * 4 + bgp * 2 + 0) * 16) * 64 * 8;
        const u16* eb1 = aembf + ((size_t)(s * 4 + bgp * 2 + 1) * 16) * 64 * 8;

        f32x4 acc00 = {0.f,0.f,0.f,0.f};   // m-tile 0, cols 0..15
        f32x4 acc01 = {0.f,0.f,0.f,0.f};   // m-tile 0, cols 16..31
        f32x4 acc10 = {0.f,0.f,0.f,0.f};   // m-tile 1
        f32x4 acc11 = {0.f,0.f,0.f,0.f};

#pragma unroll
        for (int tkt = 0; tkt < 12; ++tkt) {
            int kt = w * 12 + tkt;
            bf16x8 a0, a1;
            if (kt < 32) {
                a0 = *(const bf16x8*)(hb0 + ((size_t)kt * 64 + lane) * 8);
                a1 = *(const bf16x8*)(hb1 + ((size_t)kt * 64 + lane) * 8);
            } else {
                a0 = *(const bf16x8*)(eb0 + ((size_t)(kt - 32) * 64 + lane) * 8);
                a1 = *(const bf16x8*)(eb1 + ((size_t)(kt - 32) * 64 + lane) * 8);
            }
            acc00 = __builtin_amdgcn_mfma_f32_16x16x32_bf16(a0, wf[tkt][0], acc00, 0, 0, 0);
            acc01 = __builtin_amdgcn_mfma_f32_16x16x32_bf16(a0, wf[tkt][1], acc01, 0, 0, 0);
            acc10 = __builtin_amdgcn_mfma_f32_16x16x32_bf16(a1, wf[tkt][0], acc10, 0, 0, 0);
            acc11 = __builtin_amdgcn_mfma_f32_16x16x32_bf16(a1, wf[tkt][1], acc11, 0, 0, 0);
        }

        {   // D layout: row m=(lane>>4)*4+r, col n=lane&15
            int mrow = (lane >> 4) * 4;
#pragma unroll
            for (int r = 0; r < 4; ++r) {
                part[w][mrow + r][n16]           = acc00[r];
                part[w][mrow + r][16 + n16]      = acc01[r];
                part[w][16 + mrow + r][n16]      = acc10[r];
                part[w][16 + mrow + r][16 + n16] = acc11[r];
            }
        }
        __syncthreads();

        float gv[4];
#pragma unroll
        for (int g = 0; g < 4; ++g) {
            int n = g * 8 + uu;
            gv[g] = part[0][mloc][n] + part[1][mloc][n]
                  + part[2][mloc][n] + part[3][mloc][n] + bias_g[g];
        }
        float iS = sigf(gv[0]);
        float fS = sigf(gv[1]);
        float gT = tanhf(gv[2]);
        float oS = sigf(gv[3]);
        c_reg = fS * c_reg + iS * gT;
        c_reg = fminf(20.0f, fmaxf(-20.0f, c_reg));
        float hN = oS * tanhf(c_reg);

        hfB[hsc] = f2bf(hN);
        if (s == NS - 1) out_h[be * NH + je] = hN;

        // ---- grid barrier (2-level, monotonic) ----
        __threadfence();
        __syncthreads();
        if (tid == 0) {
            u32 tgt = (u32)(s + 1);
            u32 a = __hip_atomic_fetch_add(&bar[grp * 32], 1u,
                                           __ATOMIC_RELEASE, __HIP_MEMORY_SCOPE_AGENT);
            if (a == 32u * tgt - 1u) {
                u32 r = __hip_atomic_fetch_add(&bar[256], 1u,
                                               __ATOMIC_ACQ_REL, __HIP_MEMORY_SCOPE_AGENT);
                if (r == 8u * tgt - 1u)
                    __hip_atomic_store(&bar[320], tgt,
                                       __ATOMIC_RELEASE, __HIP_MEMORY_SCOPE_AGENT);
            }
            while (__hip_atomic_load(&bar[320], __ATOMIC_ACQUIRE,
                                     __HIP_MEMORY_SCOPE_AGENT) < tgt)
                __builtin_amdgcn_s_sleep(1);
        }
        __syncthreads();
    }

    out_c[be * NH + je] = c_reg;
}

// ---------------------------------------------------------------------------
// Per-step fallback path (R10-proven, bit-identical results)
// ---------------------------------------------------------------------------
template<bool EMBF>
__device__ __forceinline__ void step_frag_body(
    const int* __restrict__ x, const float* __restrict__ emb,
    const u16* __restrict__ wpkf, const u16* __restrict__ aembf,
    const u16* __restrict__ hfA, u16* __restrict__ hfB,
    const float* __restrict__ bsum,
    float* __restrict__ cstate, float* __restrict__ out_h, int s, int last)
{
    const int tid  = threadIdx.x;
    const int lane = tid & 63;
    const int w    = tid >> 6;
    const int blk  = blockIdx.x;
    const int cg   = blk & 127;
    const int bg   = blk >> 7;

    __shared__ float part[4][16][33];
    const int n16 = lane & 15;

    int tok = 0;
    if (!EMBF) tok = clamptok(x[(bg * 16 + n16) * NS + s]);

    const u16* wb = wpkf + (size_t)cg * 48 * 2 * 64 * 8;
    const u16* hb = hfA + (size_t)bg * 32 * 64 * 8;
    const u16* eb = EMBF ? (aembf + ((size_t)(s * 4 + bg) * 16) * 64 * 8) : nullptr;

    f32x4 acc0 = {0.f,0.f,0.f,0.f};
    f32x4 acc1 = {0.f,0.f,0.f,0.f};

#pragma unroll
    for (int tkt = 0; tkt < 12; ++tkt) {
        int kt = w * 12 + tkt;
        bf16x8 wf0 = *(const bf16x8*)(wb + ((size_t)(kt * 2 + 0) * 64 + lane) * 8);
        bf16x8 wf1 = *(const bf16x8*)(wb + ((size_t)(kt * 2 + 1) * 64 + lane) * 8);
        bf16x8 a0;
        if (kt < 32) {
            a0 = *(const bf16x8*)(hb + ((size_t)kt * 64 + lane) * 8);
        } else if (EMBF) {
            a0 = *(const bf16x8*)(eb + ((size_t)(kt - 32) * 64 + lane) * 8);
        } else {
            int kq = (lane >> 4) * 8;
            const float* ep = emb + (size_t)tok * NE + (kt - 32) * 32 + kq;
            a0 = pack8(*(const float4*)ep, *(const float4*)(ep + 4));
        }
        acc0 = __builtin_amdgcn_mfma_f32_16x16x32_bf16(a0, wf0, acc0, 0, 0, 0);
        acc1 = __builtin_amdgcn_mfma_f32_16x16x32_bf16(a0, wf1, acc1, 0, 0, 0);
    }

    {
        int mrow = (lane >> 4) * 4;
#pragma unroll
        for (int r = 0; r < 4; ++r) {
            part[w][mrow + r][n16]      = acc0[r];
            part[w][mrow + r][16 + n16] = acc1[r];
        }
    }
    __syncthreads();

    if (tid < 128) {
        const int mloc = tid >> 3, uu = tid & 7;
        const int be = bg * 16 + mloc, je = cg * 8 + uu;
        float gv[4];
#pragma unroll
        for (int g = 0; g < 4; ++g) {
            int n = g * 8 + uu;
            gv[g] = part[0][mloc][n] + part[1][mloc][n]
                  + part[2][mloc][n] + part[3][mloc][n] + bsum[g * NH + je];
        }
        float iS = sigf(gv[0]);
        float fS = sigf(gv[1]);
        float gT = tanhf(gv[2]);
        float oS = sigf(gv[3]);
        float c_new = fS * cstate[be * NH + je] + iS * gT;
        c_new = fminf(20.0f, fmaxf(-20.0f, c_new));
        float hN = oS * tanhf(c_new);
        cstate[be * NH + je] = c_new;

        int kth = je >> 5, r = je & 31;
        int lane2 = (r >> 3) * 16 + mloc;
        hfB[((size_t)(bg * 32 + kth) * 64 + lane2) * 8 + (r & 7)] = f2bf(hN);
        if (last) out_h[be * NH + je] = hN;
    }
}

__global__ void __launch_bounds__(256)
step_frag_a(const u16* __restrict__ wpkf, const u16* __restrict__ aembf,
            const u16* __restrict__ hfA, u16* __restrict__ hfB,
            const float* __restrict__ bsum,
            float* __restrict__ cstate, float* __restrict__ out_h,
            int s, int last) {
    step_frag_body<true>(nullptr, nullptr, wpkf, aembf, hfA, hfB,
                         bsum, cstate, out_h, s, last);
}

__global__ void __launch_bounds__(256)
step_frag_b(const int* __restrict__ x, const float* __restrict__ emb,
            const u16* __restrict__ wpkf,
            const u16* __restrict__ hfA, u16* __restrict__ hfB,
            const float* __restrict__ bsum,
            float* __restrict__ cstate, float* __restrict__ out_h,
            int s, int last) {
    step_frag_body<false>(x, emb, wpkf, nullptr, hfA, hfB,
                          bsum, cstate, out_h, s, last);
}

// ---------------------------------------------------------------------------
// Raw fallback (tiny ws): f32 weights + in-flight pack, f32 h ping.
// ---------------------------------------------------------------------------
__global__ void __launch_bounds__(256)
lstm_step_raw(const int* __restrict__ x, const float* __restrict__ emb,
              const float* __restrict__ Wih, const float* __restrict__ Whh,
              const float* __restrict__ bih, const float* __restrict__ bhh,
              const float* __restrict__ hA, float* __restrict__ hB,
              float* __restrict__ cbuf, int s) {
    const int tid  = threadIdx.x;
    const int lane = tid & 63;
    const int w    = tid >> 6;
    const int blk  = blockIdx.x;
    const int cg   = blk & 127;
    const int bg   = blk >> 7;
    const int u0   = cg * 8;
    const int b0   = bg * 16;

    __shared__ float part[4][16][33];
    const int n16 = lane & 15;
    const int kq  = (lane >> 4) * 8;
    const int tok = clamptok(x[(b0 + n16) * NS + s]);

    const int nl0 = n16, nl1 = 16 + n16;
    const int r0 = (nl0 >> 3) * NH + u0 + (nl0 & 7);
    const int r1 = (nl1 >> 3) * NH + u0 + (nl1 & 7);

    f32x4 acc0 = {0.f,0.f,0.f,0.f};
    f32x4 acc1 = {0.f,0.f,0.f,0.f};

#pragma unroll
    for (int tkt = 0; tkt < 12; ++tkt) {
        int kt = w * 12 + tkt;
        int ko = kt * 32 + kq;
        const float *s0, *s1;
        if (kt < 32) { s0 = Whh + (size_t)r0 * NH + ko; s1 = Whh + (size_t)r1 * NH + ko; }
        else         { s0 = Wih + (size_t)r0 * NE + (ko - NH); s1 = Wih + (size_t)r1 * NE + (ko - NH); }
        bf16x8 wf0 = pack8(*(const float4*)s0, *(const float4*)(s0 + 4));
        bf16x8 wf1 = pack8(*(const float4*)s1, *(const float4*)(s1 + 4));
        bf16x8 a0;
        if (kt < 32) {
            const float* hp = hA + (size_t)(b0 + n16) * NH + ko;
            a0 = pack8(*(const float4*)hp, *(const float4*)(hp + 4));
        } else {
            const float* ep = emb + (size_t)tok * NE + (ko - NH);
            a0 = pack8(*(const float4*)ep, *(const float4*)(ep + 4));
        }
        acc0 = __builtin_amdgcn_mfma_f32_16x16x32_bf16(a0, wf0, acc0, 0, 0, 0);
        acc1 = __builtin_amdgcn_mfma_f32_16x16x32_bf16(a0, wf1, acc1, 0, 0, 0);
    }

    {
        int mrow = (lane >> 4) * 4;
#pragma unroll
        for (int r = 0; r < 4; ++r) {
            part[w][mrow + r][n16]      = acc0[r];
            part[w][mrow + r][16 + n16] = acc1[r];
        }
    }
    __syncthreads();

    if (tid < 128) {
        const int mloc = tid >> 3, uu = tid & 7;
        const int be = b0 + mloc, je = u0 + uu;
        float gv[4];
#pragma unroll
        for (int g = 0; g < 4; ++g) {
            int n = g * 8 + uu;
            gv[g] = part[0][mloc][n] + part[1][mloc][n]
                  + part[2][mloc][n] + part[3][mloc][n]
                  + bih[g * NH + je] + bhh[g * NH + je];
        }
        float iS = sigf(gv[0]);
        float fS = sigf(gv[1]);
        float gT = tanhf(gv[2]);
        float oS = sigf(gv[3]);
        float c_new = fS * cbuf[be * NH + je] + iS * gT;
        c_new = fminf(20.0f, fmaxf(-20.0f, c_new));
        float hN = oS * tanhf(c_new);
        cbuf[be * NH + je] = c_new;
        hB[be * NH + je]   = hN;
    }
}

__global__ void final_fc_simple(const float* __restrict__ fc_w,
                                const float* __restrict__ fc_b,
                                float* __restrict__ out) {
    __shared__ float red[64][5];
    const float* out_h = out + 64;
    int t = threadIdx.x;
    int b = t >> 2, q = t & 3;
    const float* hp = out_h + b * NH + q * 256;
    const float* wp = fc_w + q * 256;
    float sacc = 0.f;
#pragma unroll 4
    for (int i = 0; i < 64; ++i) {
        float4 hv = ((const float4*)hp)[i];
        float4 wv = ((const float4*)wp)[i];
        sacc += hv.x * wv.x + hv.y * wv.y + hv.z * wv.z + hv.w * wv.w;
    }
    red[b][q] = sacc;
    __syncthreads();
    if (q == 0) {
        float tot = red[b][0] + red[b][1] + red[b][2] + red[b][3] + fc_b[0];
        out[b] = 1.0f / (1.0f + expf(-tot));
    }
}

extern "C" void kernel_launch(void* const* d_in, const int* in_sizes, int n_in,
                              void* d_out, int out_size, void* d_ws, size_t ws_size,
                              hipStream_t stream) {
    // order: x, h0, c0, emb, W_ih, W_hh, b_ih, b_hh, fc_w, fc_b
    const int*   x   = (const int*)d_in[0];
    const float* h0  = (const float*)d_in[1];
    const float* c0  = (const float*)d_in[2];
    const float* emb = (const float*)d_in[3];
    const float* Wih = (const float*)d_in[4];
    const float* Whh = (const float*)d_in[5];
    const float* bih = (const float*)d_in[6];
    const float* bhh = (const float*)d_in[7];
    const float* fcw = (const float*)d_in[8];
    const float* fcb = (const float*)d_in[9];

    float* out   = (float*)d_out;
    float* out_h = out + 64;
    float* out_c = out + 64 + NB * NH;

    const size_t needA = (size_t)WPKF_BYTES + HFRAG_BYTES + AEMBF_BYTES
                       + BSUM_BYTES + BAR_BYTES;
    const size_t needB = (size_t)WPKF_BYTES + HFRAG_BYTES + BSUM_BYTES;
    const bool tierA = ws_size >= needA;
    const bool tierB = !tierA && ws_size >= needB;

    hipLaunchKernelGGL(init_state, dim3(64), dim3(256), 0, stream, h0, c0, out);

    if (tierA || tierB) {
        u16* wpkf  = (u16*)d_ws;
        u16* hfrag = (u16*)((char*)d_ws + WPKF_BYTES);
        u16* hf0 = hfrag;
        u16* hf1 = hfrag + HFRAG_BYTES / 4;  // u16 elems per parity
        char* after = (char*)d_ws + WPKF_BYTES + HFRAG_BYTES;
        u16*   aembf = tierA ? (u16*)after : nullptr;
        float* bsum  = (float*)(after + (tierA ? AEMBF_BYTES : 0));
        u32*   bar   = (u32*)((char*)bsum + BSUM_BYTES);

        hipLaunchKernelGGL(init_hfrag, dim3(128), dim3(64), 0, stream, h0, hf0);
        hipLaunchKernelGGL(prep_wfrag, dim3(6144), dim3(128), 0, stream,
                           Wih, Whh, wpkf);
        hipLaunchKernelGGL(prep_bsum, dim3(16), dim3(256), 0, stream,
                           bih, bhh, bsum);
        if (tierA)
            hipLaunchKernelGGL(prep_aembf, dim3(2048), dim3(256), 0, stream,
                               x, emb, aembf);

        bool done = false;
        if (tierA) {
            hipLaunchKernelGGL(zero_bar, dim3(1), dim3(256), 0, stream, bar);
            void* args[] = { (void*)&wpkf, (void*)&aembf, (void*)&hf0, (void*)&hf1,
                             (void*)&c0, (void*)&bsum, (void*)&bar, (void*)&out };
            hipError_t e = hipLaunchCooperativeKernel((void*)lstm_persist,
                                                      dim3(256), dim3(256),
                                                      args, 0, stream);
            done = (e == hipSuccess);
        }
        if (!done) {
            for (int s = 0; s < NS; ++s) {
                const u16* hfA = (s & 1) ? hf1 : hf0;
                u16*       hfB = (s & 1) ? hf0 : hf1;
                int last = (s == NS - 1);
                if (tierA)
                    hipLaunchKernelGGL(step_frag_a, dim3(512), dim3(256), 0, stream,
                                       wpkf, aembf, hfA, hfB, bsum,
                                       out_c, out_h, s, last);
                else
                    hipLaunchKernelGGL(step_frag_b, dim3(512), dim3(256), 0, stream,
                                       x, emb, wpkf, hfA, hfB, bsum,
                                       out_c, out_h, s, last);
            }
        }
    } else {
        float* wsH = (float*)d_ws;
        for (int s = 0; s < NS; ++s) {
            const float* hA = (s & 1) ? wsH : out_h;
            float*       hB = (s & 1) ? out_h : wsH;
            hipLaunchKernelGGL(lstm_step_raw, dim3(512), dim3(256), 0, stream,
                               x, emb, Wih, Whh, bih, bhh, hA, hB, out_c, s);
        }
    }

    hipLaunchKernelGGL(final_fc_simple, dim3(1), dim3(256), 0, stream,
                       fcw, fcb, out);
}

// Round 12
// 3452.856 us; speedup vs baseline: 5.2268x; 5.2268x over previous
//
#include <hip/hip_runtime.h>

typedef unsigned short u16;
typedef unsigned int   u32;

typedef __bf16 bf16x8 __attribute__((ext_vector_type(8)));
typedef float  f32x4  __attribute__((ext_vector_type(4)));

#define NB   64
#define NS   512
#define NE   512
#define NH   1024
#define NK   1536
#define NV   32000

#define WPKF_BYTES  12582912u   // bf16 frags [128 cg][48 kt][2 f][64 lane][8]
#define HFRAG_BYTES 262144u     // bf16 frags 2 par x [4 bg][32 kt][64 lane][8]
#define AEMBF_BYTES 33554432u   // bf16 frags [512 s][4 bg][16 kt][64 lane][8]
#define BSUM_BYTES  16384u      // f32 [4096]

__device__ __forceinline__ u16 f2bf(float f) {
    u32 u = __builtin_bit_cast(u32, f);
    u += 0x7fffu + ((u >> 16) & 1u);       // RNE
    return (u16)(u >> 16);
}
__device__ __forceinline__ bf16x8 pack8(float4 a, float4 b) {
    union { u16 u[8]; bf16x8 v; } o;
    o.u[0]=f2bf(a.x); o.u[1]=f2bf(a.y); o.u[2]=f2bf(a.z); o.u[3]=f2bf(a.w);
    o.u[4]=f2bf(b.x); o.u[5]=f2bf(b.y); o.u[6]=f2bf(b.z); o.u[7]=f2bf(b.w);
    return o.v;
}
// fast sigmoid/tanh: __expf + hw reciprocal; rel err ~1e-6, far under threshold
__device__ __forceinline__ float sigf(float x) {
    return __frcp_rn(1.0f + __expf(-x));
}
__device__ __forceinline__ float tanhf_fast(float x) {
    return 1.0f - 2.0f * __frcp_rn(__expf(2.0f * x) + 1.0f);
}
__device__ __forceinline__ int clamptok(int t) {
    return t < 0 ? 0 : (t >= NV ? NV - 1 : t);
}

// ---------------------------------------------------------------------------
// Prep kernels (R9/R10-proven)
// ---------------------------------------------------------------------------
__global__ void init_state(const float* __restrict__ h0,
                           const float* __restrict__ c0,
                           float* __restrict__ out) {
    int i = blockIdx.x * 256 + threadIdx.x;
    float* out_h = out + 64;
    float* out_c = out + 64 + NB * NH;
    ((float4*)out_h)[i] = ((const float4*)h0)[i];
    ((float4*)out_c)[i] = ((const float4*)c0)[i];
}

__global__ void init_hfrag(const float* __restrict__ h0,
                           u16* __restrict__ hfrag0) {
    int blk = blockIdx.x, lane = threadIdx.x;
    int bg = blk >> 5, kt = blk & 31;
    int n16 = lane & 15, quad = lane >> 4;
    int b = bg * 16 + n16;
    int k = kt * 32 + quad * 8;
    const float* src = h0 + (size_t)b * NH + k;
    union { bf16x8 v; uint4 q; } o;
    o.v = pack8(*(const float4*)src, *(const float4*)(src + 4));
    *(uint4*)(hfrag0 + ((size_t)blk * 64 + lane) * 8) = o.q;
}

__global__ void prep_wfrag(const float* __restrict__ Wih,
                           const float* __restrict__ Whh,
                           u16* __restrict__ wpkf) {
    int blk = blockIdx.x, t = threadIdx.x;
    int cg = blk / 48, kt = blk % 48;
    int f = t >> 6, lane = t & 63;
    int n16 = lane & 15, quad = lane >> 4;
    int nl = f * 16 + n16;
    int j = (nl >> 3) * NH + cg * 8 + (nl & 7);
    int k = kt * 32 + quad * 8;
    const float* src = (k < NH) ? (Whh + (size_t)j * NH + k)
                                : (Wih + (size_t)j * NE + (k - NH));
    union { bf16x8 v; uint4 q; } o;
    o.v = pack8(*(const float4*)src, *(const float4*)(src + 4));
    *(uint4*)(wpkf + (((size_t)blk * 2 + f) * 64 + lane) * 8) = o.q;
}

__global__ void prep_aembf(const int* __restrict__ x,
                           const float* __restrict__ emb,
                           u16* __restrict__ aembf) {
    int blk = blockIdx.x, t = threadIdx.x;
    int s = blk >> 2, bg = blk & 3;
#pragma unroll
    for (int i = 0; i < 4; ++i) {
        int u = t + i * 256;
        int kt16 = u >> 6, lane = u & 63;
        int n16 = lane & 15, quad = lane >> 4;
        int b = bg * 16 + n16;
        int tok = clamptok(x[b * NS + s]);
        const float* ep = emb + (size_t)tok * NE + kt16 * 32 + quad * 8;
        union { bf16x8 v; uint4 q; } o;
        o.v = pack8(*(const float4*)ep, *(const float4*)(ep + 4));
        *(uint4*)(aembf + (((size_t)blk * 16 + kt16) * 64 + lane) * 8) = o.q;
    }
}

__global__ void prep_bsum(const float* __restrict__ bih,
                          const float* __restrict__ bhh,
                          float* __restrict__ bsum) {
    int i = blockIdx.x * 256 + threadIdx.x;
    bsum[i] = bih[i] + bhh[i];
}

// ---------------------------------------------------------------------------
// Per-step fragment kernel. 512 blocks x 256 (4 waves K-split).
// XCD swizzle: cg = blk & 127 -> all 4 bg-copies of a cg share an XCD; that
// XCD's 16 cg x 96 KB weight slice stays L2-resident across all 512 steps.
// LDS part padded to 36 (R11 counters: stride 33 gave 8-way diagonal
// conflicts, 6.7e7 total; 36 -> worst 2-way = free).
// c + bias prefetched before the K-loop to hide global latency.
// ---------------------------------------------------------------------------
template<bool EMBF>
__device__ __forceinline__ void step_frag_body(
    const int* __restrict__ x, const float* __restrict__ emb,
    const u16* __restrict__ wpkf, const u16* __restrict__ aembf,
    const u16* __restrict__ hfA, u16* __restrict__ hfB,
    const float* __restrict__ bsum,
    float* __restrict__ cstate, float* __restrict__ out_h, int s, int last)
{
    const int tid  = threadIdx.x;
    const int lane = tid & 63;
    const int w    = tid >> 6;
    const int blk  = blockIdx.x;
    const int cg   = blk & 127;
    const int bg   = blk >> 7;

    __shared__ float part[4][16][36];
    const int n16 = lane & 15;

    // ---- epilogue prefetch (indices masked so tid>=128 reads stay in-range)
    const int mlocP = (tid >> 3) & 15;
    const int uuP   = tid & 7;
    const int beP   = bg * 16 + mlocP;
    const int jeP   = cg * 8 + uuP;
    float c_pre = cstate[beP * NH + jeP];
    float bp0 = bsum[0 * NH + jeP];
    float bp1 = bsum[1 * NH + jeP];
    float bp2 = bsum[2 * NH + jeP];
    float bp3 = bsum[3 * NH + jeP];

    int tok = 0;
    if (!EMBF) tok = clamptok(x[(bg * 16 + n16) * NS + s]);

    const u16* wb = wpkf + (size_t)cg * 48 * 2 * 64 * 8;
    const u16* hb = hfA + (size_t)bg * 32 * 64 * 8;
    const u16* eb = EMBF ? (aembf + ((size_t)(s * 4 + bg) * 16) * 64 * 8) : nullptr;

    f32x4 acc0 = {0.f,0.f,0.f,0.f};
    f32x4 acc1 = {0.f,0.f,0.f,0.f};

#pragma unroll
    for (int tkt = 0; tkt < 12; ++tkt) {
        int kt = w * 12 + tkt;
        bf16x8 wf0 = *(const bf16x8*)(wb + ((size_t)(kt * 2 + 0) * 64 + lane) * 8);
        bf16x8 wf1 = *(const bf16x8*)(wb + ((size_t)(kt * 2 + 1) * 64 + lane) * 8);
        bf16x8 a0;
        if (kt < 32) {
            a0 = *(const bf16x8*)(hb + ((size_t)kt * 64 + lane) * 8);
        } else if (EMBF) {
            a0 = *(const bf16x8*)(eb + ((size_t)(kt - 32) * 64 + lane) * 8);
        } else {
            int kq = (lane >> 4) * 8;
            const float* ep = emb + (size_t)tok * NE + (kt - 32) * 32 + kq;
            a0 = pack8(*(const float4*)ep, *(const float4*)(ep + 4));
        }
        acc0 = __builtin_amdgcn_mfma_f32_16x16x32_bf16(a0, wf0, acc0, 0, 0, 0);
        acc1 = __builtin_amdgcn_mfma_f32_16x16x32_bf16(a0, wf1, acc1, 0, 0, 0);
    }

    {   // D layout: row m=(lane>>4)*4+r (batch), col n=lane&15 (gate col)
        int mrow = (lane >> 4) * 4;
#pragma unroll
        for (int r = 0; r < 4; ++r) {
            part[w][mrow + r][n16]      = acc0[r];
            part[w][mrow + r][16 + n16] = acc1[r];
        }
    }
    __syncthreads();

    if (tid < 128) {
        float gv[4] = { bp0, bp1, bp2, bp3 };
#pragma unroll
        for (int g = 0; g < 4; ++g) {
            int n = g * 8 + uuP;
            gv[g] += part[0][mlocP][n] + part[1][mlocP][n]
                   + part[2][mlocP][n] + part[3][mlocP][n];
        }
        float iS = sigf(gv[0]);
        float fS = sigf(gv[1]);
        float gT = tanhf_fast(gv[2]);
        float oS = sigf(gv[3]);
        float c_new = fS * c_pre + iS * gT;
        c_new = fminf(20.0f, fmaxf(-20.0f, c_new));   // semantically free guard
        float hN = oS * tanhf_fast(c_new);
        cstate[beP * NH + jeP] = c_new;

        int kth = jeP >> 5, r = jeP & 31;
        int lane2 = (r >> 3) * 16 + mlocP;
        hfB[((size_t)(bg * 32 + kth) * 64 + lane2) * 8 + (r & 7)] = f2bf(hN);
        if (last) out_h[beP * NH + jeP] = hN;
    }
}

__global__ void __launch_bounds__(256)
step_frag_a(const u16* __restrict__ wpkf, const u16* __restrict__ aembf,
            const u16* __restrict__ hfA, u16* __restrict__ hfB,
            const float* __restrict__ bsum,
            float* __restrict__ cstate, float* __restrict__ out_h,
            int s, int last) {
    step_frag_body<true>(nullptr, nullptr, wpkf, aembf, hfA, hfB,
                         bsum, cstate, out_h, s, last);
}

__global__ void __launch_bounds__(256)
step_frag_b(const int* __restrict__ x, const float* __restrict__ emb,
            const u16* __restrict__ wpkf,
            const u16* __restrict__ hfA, u16* __restrict__ hfB,
            const float* __restrict__ bsum,
            float* __restrict__ cstate, float* __restrict__ out_h,
            int s, int last) {
    step_frag_body<false>(x, emb, wpkf, nullptr, hfA, hfB,
                          bsum, cstate, out_h, s, last);
}

// ---------------------------------------------------------------------------
// Raw fallback (tiny ws): f32 weights + in-flight pack, f32 h ping.
// ---------------------------------------------------------------------------
__global__ void __launch_bounds__(256)
lstm_step_raw(const int* __restrict__ x, const float* __restrict__ emb,
              const float* __restrict__ Wih, const float* __restrict__ Whh,
              const float* __restrict__ bih, const float* __restrict__ bhh,
              const float* __restrict__ hA, float* __restrict__ hB,
              float* __restrict__ cbuf, int s) {
    const int tid  = threadIdx.x;
    const int lane = tid & 63;
    const int w    = tid >> 6;
    const int blk  = blockIdx.x;
    const int cg   = blk & 127;
    const int bg   = blk >> 7;
    const int u0   = cg * 8;
    const int b0   = bg * 16;

    __shared__ float part[4][16][36];
    const int n16 = lane & 15;
    const int kq  = (lane >> 4) * 8;
    const int tok = clamptok(x[(b0 + n16) * NS + s]);

    const int nl0 = n16, nl1 = 16 + n16;
    const int r0 = (nl0 >> 3) * NH + u0 + (nl0 & 7);
    const int r1 = (nl1 >> 3) * NH + u0 + (nl1 & 7);

    f32x4 acc0 = {0.f,0.f,0.f,0.f};
    f32x4 acc1 = {0.f,0.f,0.f,0.f};

#pragma unroll
    for (int tkt = 0; tkt < 12; ++tkt) {
        int kt = w * 12 + tkt;
        int ko = kt * 32 + kq;
        const float *s0, *s1;
        if (kt < 32) { s0 = Whh + (size_t)r0 * NH + ko; s1 = Whh + (size_t)r1 * NH + ko; }
        else         { s0 = Wih + (size_t)r0 * NE + (ko - NH); s1 = Wih + (size_t)r1 * NE + (ko - NH); }
        bf16x8 wf0 = pack8(*(const float4*)s0, *(const float4*)(s0 + 4));
        bf16x8 wf1 = pack8(*(const float4*)s1, *(const float4*)(s1 + 4));
        bf16x8 a0;
        if (kt < 32) {
            const float* hp = hA + (size_t)(b0 + n16) * NH + ko;
            a0 = pack8(*(const float4*)hp, *(const float4*)(hp + 4));
        } else {
            const float* ep = emb + (size_t)tok * NE + (ko - NH);
            a0 = pack8(*(const float4*)ep, *(const float4*)(ep + 4));
        }
        acc0 = __builtin_amdgcn_mfma_f32_16x16x32_bf16(a0, wf0, acc0, 0, 0, 0);
        acc1 = __builtin_amdgcn_mfma_f32_16x16x32_bf16(a0, wf1, acc1, 0, 0, 0);
    }

    {
        int mrow = (lane >> 4) * 4;
#pragma unroll
        for (int r = 0; r < 4; ++r) {
            part[w][mrow + r][n16]      = acc0[r];
            part[w][mrow + r][16 + n16] = acc1[r];
        }
    }
    __syncthreads();

    if (tid < 128) {
        const int mloc = tid >> 3, uu = tid & 7;
        const int be = b0 + mloc, je = u0 + uu;
        float gv[4];
#pragma unroll
        for (int g = 0; g < 4; ++g) {
            int n = g * 8 + uu;
            gv[g] = part[0][mloc][n] + part[1][mloc][n]
                  + part[2][mloc][n] + part[3][mloc][n]
                  + bih[g * NH + je] + bhh[g * NH + je];
        }
        float iS = sigf(gv[0]);
        float fS = sigf(gv[1]);
        float gT = tanhf_fast(gv[2]);
        float oS = sigf(gv[3]);
        float c_new = fS * cbuf[be * NH + je] + iS * gT;
        c_new = fminf(20.0f, fmaxf(-20.0f, c_new));
        float hN = oS * tanhf_fast(c_new);
        cbuf[be * NH + je] = c_new;
        hB[be * NH + je]   = hN;
    }
}

__global__ void final_fc_simple(const float* __restrict__ fc_w,
                                const float* __restrict__ fc_b,
                                float* __restrict__ out) {
    __shared__ float red[64][5];
    const float* out_h = out + 64;
    int t = threadIdx.x;
    int b = t >> 2, q = t & 3;
    const float* hp = out_h + b * NH + q * 256;
    const float* wp = fc_w + q * 256;
    float sacc = 0.f;
#pragma unroll 4
    for (int i = 0; i < 64; ++i) {
        float4 hv = ((const float4*)hp)[i];
        float4 wv = ((const float4*)wp)[i];
        sacc += hv.x * wv.x + hv.y * wv.y + hv.z * wv.z + hv.w * wv.w;
    }
    red[b][q] = sacc;
    __syncthreads();
    if (q == 0) {
        float tot = red[b][0] + red[b][1] + red[b][2] + red[b][3] + fc_b[0];
        out[b] = 1.0f / (1.0f + expf(-tot));
    }
}

extern "C" void kernel_launch(void* const* d_in, const int* in_sizes, int n_in,
                              void* d_out, int out_size, void* d_ws, size_t ws_size,
                              hipStream_t stream) {
    // order: x, h0, c0, emb, W_ih, W_hh, b_ih, b_hh, fc_w, fc_b
    const int*   x   = (const int*)d_in[0];
    const float* h0  = (const float*)d_in[1];
    const float* c0  = (const float*)d_in[2];
    const float* emb = (const float*)d_in[3];
    const float* Wih = (const float*)d_in[4];
    const float* Whh = (const float*)d_in[5];
    const float* bih = (const float*)d_in[6];
    const float* bhh = (const float*)d_in[7];
    const float* fcw = (const float*)d_in[8];
    const float* fcb = (const float*)d_in[9];

    float* out   = (float*)d_out;
    float* out_h = out + 64;
    float* out_c = out + 64 + NB * NH;       // c state in-place

    const size_t needA = (size_t)WPKF_BYTES + HFRAG_BYTES + AEMBF_BYTES + BSUM_BYTES;
    const size_t needB = (size_t)WPKF_BYTES + HFRAG_BYTES + BSUM_BYTES;
    const bool tierA = ws_size >= needA;
    const bool tierB = !tierA && ws_size >= needB;

    hipLaunchKernelGGL(init_state, dim3(64), dim3(256), 0, stream, h0, c0, out);

    if (tierA || tierB) {
        u16* wpkf  = (u16*)d_ws;
        u16* hfrag = (u16*)((char*)d_ws + WPKF_BYTES);
        u16* hf0 = hfrag;
        u16* hf1 = hfrag + HFRAG_BYTES / 4;  // u16 elems per parity
        char* after = (char*)d_ws + WPKF_BYTES + HFRAG_BYTES;
        u16*   aembf = tierA ? (u16*)after : nullptr;
        float* bsum  = (float*)(after + (tierA ? AEMBF_BYTES : 0));

        hipLaunchKernelGGL(init_hfrag, dim3(128), dim3(64), 0, stream, h0, hf0);
        hipLaunchKernelGGL(prep_wfrag, dim3(6144), dim3(128), 0, stream,
                           Wih, Whh, wpkf);
        hipLaunchKernelGGL(prep_bsum, dim3(16), dim3(256), 0, stream,
                           bih, bhh, bsum);
        if (tierA)
            hipLaunchKernelGGL(prep_aembf, dim3(2048), dim3(256), 0, stream,
                               x, emb, aembf);

        for (int s = 0; s < NS; ++s) {
            const u16* hfA = (s & 1) ? hf1 : hf0;
            u16*       hfB = (s & 1) ? hf0 : hf1;
            int last = (s == NS - 1);
            if (tierA)
                hipLaunchKernelGGL(step_frag_a, dim3(512), dim3(256), 0, stream,
                                   wpkf, aembf, hfA, hfB, bsum,
                                   out_c, out_h, s, last);
            else
                hipLaunchKernelGGL(step_frag_b, dim3(512), dim3(256), 0, stream,
                                   x, emb, wpkf, hfA, hfB, bsum,
                                   out_c, out_h, s, last);
        }
    } else {
        float* wsH = (float*)d_ws;
        for (int s = 0; s < NS; ++s) {
            const float* hA = (s & 1) ? wsH : out_h;
            float*       hB = (s & 1) ? out_h : wsH;   // s=511 odd -> out_h
            hipLaunchKernelGGL(lstm_step_raw, dim3(512), dim3(256), 0, stream,
                               x, emb, Wih, Whh, bih, bhh, hA, hB, out_c, s);
        }
    }

    hipLaunchKernelGGL(final_fc_simple, dim3(1), dim3(256), 0, stream,
                       fcw, fcb, out);
}